// Round 4
// baseline (159.671 us; speedup 1.0000x reference)
//
#include <hip/hip_runtime.h>
#include <cstdint>
#include <cstddef>

#define BB  2
#define TT  2048
#define CC  1024
#define NHH 16
#define HSS 64
#define BT  (BB*TT)   // 4096

typedef unsigned short u16;
typedef unsigned int u32;
typedef __attribute__((ext_vector_type(2))) unsigned int u32x2;
typedef _Float16 f16;
typedef __attribute__((ext_vector_type(8))) _Float16 f16x8;
typedef __attribute__((ext_vector_type(8))) __bf16 bf16x8;
typedef __attribute__((ext_vector_type(4))) float f32x4;

__device__ __forceinline__ u16 f2bf(float f) {
    union { float f; u32 u; } x; x.f = f;
    return (u16)((x.u + 0x7fffu + ((x.u >> 16) & 1u)) >> 16);
}
__device__ __forceinline__ u16 f2h(float f) {
    union { f16 h; u16 u; } x; x.h = (f16)f;
    return x.u;
}
// packed f32 pair -> bf16x2 in one u32 (RNE), single VALU op
__device__ __forceinline__ u32 cvtpk_bf16(float lo, float hi) {
    u32 r;
    asm("v_cvt_pk_bf16_f32 %0, %1, %2" : "=v"(r) : "v"(lo), "v"(hi));
    return r;
}

#define MFMA_BF(a,b,c) __builtin_amdgcn_mfma_f32_16x16x32_bf16((a),(b),(c),0,0,0)
#define MFMA_F16(a,b,c) __builtin_amdgcn_mfma_f32_16x16x32_f16((a),(b),(c),0,0,0)

// async global->LDS, 16B/lane; LDS dest = wave-uniform base + lane*16
__device__ __forceinline__ void gld16(const u16* g, u16* l) {
    __builtin_amdgcn_global_load_lds(
        (const __attribute__((address_space(1))) unsigned int*)g,
        (__attribute__((address_space(3))) unsigned int*)l, 16, 0, 0);
}

// ---------------------------------------------------------------------------
// convert_x: x fp32 -> Xf fp16.
// ---------------------------------------------------------------------------
__global__ __launch_bounds__(256) void convert_x(
    const float* __restrict__ X, u16* __restrict__ Xf)
{
    const int idx = (blockIdx.x * 256 + threadIdx.x) * 8;
    const float4 a = *(const float4*)&X[idx];
    const float4 b = *(const float4*)&X[idx + 4];
    float v[8] = {a.x, a.y, a.z, a.w, b.x, b.y, b.z, b.w};
    union { uint4 u; u16 s[8]; } H;
    #pragma unroll
    for (int u = 0; u < 8; ++u) H.s[u] = f2h(v[u]);
    *(uint4*)&Xf[idx] = H.u;
}

// ---------------------------------------------------------------------------
// convert_w: W [k][n] fp32 -> WT [n][k] fp16 (z=0: Wk, z=1: Wv).
// ---------------------------------------------------------------------------
__global__ __launch_bounds__(256) void convert_w(
    const float* __restrict__ Wk, const float* __restrict__ Wv,
    u16* __restrict__ WkT, u16* __restrict__ WvT)
{
    const bool isK = (blockIdx.z == 0);
    const float* W = isK ? Wk : Wv;
    u16* WT = isK ? WkT : WvT;
    __shared__ __align__(16) u16 LH[64][72];
    const int tid = threadIdx.x;
    const int k0 = blockIdx.y * 64, n0 = blockIdx.x * 64;
    {
        const int row = tid >> 2, coff = (tid & 3) * 16;
        const float* g = &W[(size_t)(k0 + row) * CC + n0 + coff];
        #pragma unroll
        for (int u = 0; u < 16; ++u) LH[row][coff + u] = f2h(g[u]);
    }
    __syncthreads();
    {
        const int n = tid >> 2, kc = (tid & 3) * 16;
        union { uint4 u[2]; u16 s[16]; } Hq;
        #pragma unroll
        for (int u = 0; u < 16; ++u) Hq.s[u] = LH[kc + u][n];
        uint4* ph = (uint4*)&WT[(size_t)(n0 + n) * CC + k0 + kc];
        ph[0] = Hq.u[0]; ph[1] = Hq.u[1];
    }
}

// ---------------------------------------------------------------------------
// proj_kernel: 128x128 fp16 GEMM, BK=64, DOUBLE-BUFFERED gld16 staging
// (1 barrier/k-iter), XCD-swizzled grid, epilogues via LDS transpose.
// z=0: Kproj -> Kf fp16 [t][c]. z=1: V -> Vt bf16 head-transposed [b][h][d][T].
// ---------------------------------------------------------------------------
__global__ __launch_bounds__(256) void proj_kernel(
    const u16* __restrict__ Xf, const u16* __restrict__ WkT,
    const u16* __restrict__ WvT,
    const float* __restrict__ bk, const float* __restrict__ bv,
    u16* __restrict__ Kf, u16* __restrict__ Vt)
{
    __shared__ u16 SM[4][8192];   // [0..1]: A dbuf, [2..3]: B dbuf; epilogue reuse

    const int id = blockIdx.x;
    const int xcd = id & 7, idx = id >> 3;
    const int z = idx >> 5, rem = idx & 31;
    const int n0 = (rem & 7) * 128;
    const int m0 = (xcd * 4 + (rem >> 3)) * 128;
    const bool isK = (z == 0);
    const u16* WT = isK ? WkT : WvT;

    const int tid = threadIdx.x;
    const int w = tid >> 6, lane = tid & 63;
    const int quad = lane >> 4, l15 = lane & 15;
    const int wm = (w >> 1) * 64, wn = (w & 1) * 64;

    // staging: waves 0,1 -> A (Xf rows m0..), waves 2,3 -> B (WT rows n0..)
    const u16* src = (w < 2) ? Xf : WT;
    const int rb = (w < 2) ? m0 : n0;
    int srow[8], scg[8];
    #pragma unroll
    for (int t = 0; t < 8; ++t) {
        int ci = (w & 1) * 512 + t * 64 + lane;
        srow[t] = ci >> 3;
        scg[t] = ((ci & 7) - srow[t]) & 7;
    }
    const int sbase = (w & 1) * 4096;

    f32x4 acc[4][4] = {};

    // prologue stage k=0 into buf 0
    {
        u16* dst = ((w < 2) ? SM[0] : SM[2]) + sbase;
        #pragma unroll
        for (int t = 0; t < 8; ++t)
            gld16(src + (size_t)(rb + srow[t]) * CC + scg[t] * 8, dst + t * 512);
    }

    for (int ki = 0; ki < 16; ++ki) {
        const int buf = ki & 1;
        __syncthreads();           // buf ready; prev buf reads done
        if (ki < 15) {
            u16* dst = ((w < 2) ? SM[buf ^ 1] : SM[2 + (buf ^ 1)]) + sbase;
            const int k0n = (ki + 1) * 64;
            #pragma unroll
            for (int t = 0; t < 8; ++t)
                gld16(src + (size_t)(rb + srow[t]) * CC + k0n + scg[t] * 8,
                      dst + t * 512);
        }
        const u16* Ab = SM[buf];
        const u16* Bb = SM[2 + buf];
        #pragma unroll
        for (int kk = 0; kk < 2; ++kk) {
            f16x8 ah[4];
            #pragma unroll
            for (int i = 0; i < 4; ++i) {
                const int row = wm + i * 16 + l15;
                const int cp = ((kk * 4 + quad + row) & 7) * 8;
                ah[i] = *(const f16x8*)&Ab[row * 64 + cp];
            }
            #pragma unroll
            for (int j = 0; j < 4; ++j) {
                const int rowb = wn + j * 16 + l15;
                const int cpb = ((kk * 4 + quad + rowb) & 7) * 8;
                f16x8 bh_ = *(const f16x8*)&Bb[rowb * 64 + cpb];
                #pragma unroll
                for (int i = 0; i < 4; ++i)
                    acc[i][j] = MFMA_F16(ah[i], bh_, acc[i][j]);
            }
        }
    }

    __syncthreads();               // all compute done; reuse SM for epilogue
    u16* XL = &SM[0][0];           // stride 136 (17408 u16 = 34 KB)

    if (isK) {
        #pragma unroll
        for (int j = 0; j < 4; ++j) {
            const float bias = bk[n0 + wn + j * 16 + l15];
            #pragma unroll
            for (int i = 0; i < 4; ++i)
                #pragma unroll
                for (int r = 0; r < 4; ++r)
                    XL[(wm + i * 16 + quad * 4 + r) * 136 + wn + j * 16 + l15] =
                        f2h(acc[i][j][r] + bias);
        }
        __syncthreads();
        const int r = tid >> 1, half = tid & 1;
        #pragma unroll
        for (int t = 0; t < 8; ++t)
            *(uint4*)&Kf[(size_t)(m0 + r) * CC + n0 + half * 64 + t * 8] =
                *(const uint4*)&XL[r * 136 + half * 64 + t * 8];
    } else {
        // write transposed [n-local][t-local]: 4 consecutive t -> uint2
        #pragma unroll
        for (int j = 0; j < 4; ++j) {
            const float bias = bv[n0 + wn + j * 16 + l15];
            #pragma unroll
            for (int i = 0; i < 4; ++i) {
                uint2 pk;
                pk.x = (u32)f2bf(acc[i][j][0] + bias) |
                       ((u32)f2bf(acc[i][j][1] + bias) << 16);
                pk.y = (u32)f2bf(acc[i][j][2] + bias) |
                       ((u32)f2bf(acc[i][j][3] + bias) << 16);
                *(uint2*)&XL[(wn + j * 16 + l15) * 136 + wm + i * 16 + quad * 4] = pk;
            }
        }
        __syncthreads();
        const int nl = tid >> 1, half = tid & 1;
        const int d = (n0 + nl) & (HSS - 1), hh = (n0 + nl) >> 6;
        const int bb = m0 >> 11, tb = (m0 & (TT - 1)) + half * 64;
        const size_t gb = ((size_t)(bb * NHH + hh) * HSS + d) * TT + tb;
        #pragma unroll
        for (int t = 0; t < 8; ++t)
            *(uint4*)&Vt[gb + t * 8] = *(const uint4*)&XL[nl * 136 + half * 64 + t * 8];
    }
}

// ---------------------------------------------------------------------------
// attn: paired i-tiles (k, 31-k), split by jt-parity -> 1024 balanced blocks.
// LDS = Xs+Vs only (32 KB) -> 4 blocks/CU co-resident (the R3 blocker was
// the 18 KB P buffer capping residency at 3/CU with 4/CU needed).
// P path fully in registers: swapped QK^T leaves lane (quad,l15) holding
// S[i=l15][j=nt*16+quad*4+r]; exp -> v_cvt_pk_bf16_f32 pairs -> BUILTIN
// __builtin_amdgcn_permlane16_swap quad-redistribution (raw-asm version in
// R2 corrupted registers: cross-lane hazard waits are only inserted for
// instructions the compiler can see). k-groups land permuted pi={0,2,1,3};
// compensated by reading V B-fragments at chunk pi(quad) (free, compile-time).
// l via ones-MFMA (invariant to k-permutation). Partials (o,l) -> combine.
// ---------------------------------------------------------------------------
__global__ __launch_bounds__(256) void attn_kernel(
    const u16* __restrict__ Xf, const u16* __restrict__ Kf,
    const u16* __restrict__ Vt, float* __restrict__ po,
    float* __restrict__ pl)
{
    __shared__ u16 Xs[2][4096];               // x rows [j][d], chunk-swizzled
    __shared__ u16 Vs[2][4096];               // V^T [d][j], chunk-swizzled

    const int L = blockIdx.x;
    const int xcd = L & 7, k = (L >> 3) & 15;
    const int half = (L >> 7) & 1, grp = L >> 8;         // grp in [0,4)
    const int hb = xcd + 8 * grp;                        // hb in [0,32)
    const int h = hb & (NHH - 1), b = hb >> 4;
    const int iA = k, iB = 31 - k;
    const int i0A = iA * 64, i0B = iB * 64;

    const int tid = threadIdx.x;
    const int w = tid >> 6, lane = tid & 63;
    const int quad = lane >> 4, l15 = lane & 15;
    const int pq = ((quad & 1) << 1) | (quad >> 1);      // pi(quad)={0,2,1,3}
    const size_t rowbase = (size_t)b * TT;
    const int hd = h * HSS;
    const size_t vgbase = (size_t)(b * NHH + h) * HSS * TT;

    bf16x8 ones;
    { union { u32 u[4]; bf16x8 v; } o;
      #pragma unroll
      for (int i = 0; i < 4; ++i) o.u[i] = 0x3F803F80u;
      ones = o.v; }

    // hoist Q (projected-K) B-fragments for both tiles (row = l15)
    f16x8 qA[2], qB[2];
    #pragma unroll
    for (int c = 0; c < 2; ++c) {
        qA[c] = *(const f16x8*)&Kf[(rowbase + i0A + w * 16 + l15) * CC + hd + c * 32 + quad * 8];
        qB[c] = *(const f16x8*)&Kf[(rowbase + i0B + w * 16 + l15) * CC + hd + c * 32 + quad * 8];
    }

    // gld16 staging descriptors: 2 chunks per lane per array
    int crow[2], ccg[2], cbase[2];
    #pragma unroll
    for (int t = 0; t < 2; ++t) {
        const int ci = t * 256 + tid;
        crow[t] = ci >> 3;
        ccg[t] = ((ci & 7) - crow[t]) & 7;
        cbase[t] = (t * 256 + w * 64) * 8;
    }
    const u16* gx[2]; const u16* gv[2];
    #pragma unroll
    for (int t = 0; t < 2; ++t) {
        gx[t] = Xf + (rowbase + crow[t]) * CC + hd + ccg[t] * 8;
        gv[t] = Vt + vgbase + (size_t)crow[t] * TT + ccg[t] * 8;
    }

    // prologue: stage tile jt=half into buf 0
    {
        const int j0 = half * 64;
        #pragma unroll
        for (int t = 0; t < 2; ++t) {
            gld16(gx[t] + (size_t)j0 * CC, Xs[0] + cbase[t]);
            gld16(gv[t] + j0, Vs[0] + cbase[t]);
        }
    }

    f32x4 oA[4] = {}, oB[4] = {};
    f32x4 laA = {}, laB = {};

    for (int jt = half; jt <= iB; jt += 2) {
        const int buf = (jt >> 1) & 1;
        __syncthreads();          // buf ready (vmcnt drained); prev reads done
        if (jt + 2 <= iB) {
            const int j0n = (jt + 2) * 64;
            #pragma unroll
            for (int t = 0; t < 2; ++t) {
                gld16(gx[t] + (size_t)j0n * CC, Xs[buf ^ 1] + cbase[t]);
                gld16(gv[t] + j0n, Vs[buf ^ 1] + cbase[t]);
            }
        }
        const bool doA = (jt <= iA);

        // ---- S for both tiles, sharing xb fragments; SWAPPED operands:
        // lane (quad,l15) reg r holds S[i = w*16+l15][j = nt*16+quad*4+r],
        // C-init = -20 (softmax bias)
        f32x4 sB[4], sA[4];
        #pragma unroll
        for (int nt = 0; nt < 4; ++nt) {
            const int krow = nt * 16 + l15;
            f16x8 x0 = *(const f16x8*)&Xs[buf][krow * 64 + ((quad + krow) & 7) * 8];
            f16x8 x1 = *(const f16x8*)&Xs[buf][krow * 64 + ((quad + 4 + krow) & 7) * 8];
            f32x4 z = {-20.f, -20.f, -20.f, -20.f};
            z = MFMA_F16(x0, qB[0], z);
            z = MFMA_F16(x1, qB[1], z);
            sB[nt] = z;
            if (doA) {
                f32x4 y = {-20.f, -20.f, -20.f, -20.f};
                y = MFMA_F16(x0, qA[0], y);
                y = MFMA_F16(x1, qA[1], y);
                sA[nt] = y;
            }
        }
        if (jt == iB) {
            #pragma unroll
            for (int nt = 0; nt < 4; ++nt)
                #pragma unroll
                for (int r = 0; r < 4; ++r)
                    if (nt * 16 + quad * 4 + r > w * 16 + l15) sB[nt][r] = -1e30f;
        }
        if (doA && jt == iA) {
            #pragma unroll
            for (int nt = 0; nt < 4; ++nt)
                #pragma unroll
                for (int r = 0; r < 4; ++r)
                    if (nt * 16 + quad * 4 + r > w * 16 + l15) sA[nt][r] = -1e30f;
        }

        // ---- exp + in-register pack + permlane16_swap quad-redistribution.
        // pre-swap: pB_[nt][p] at quad q = P[i=l15][j = nt*16+q*4+2p, +2p+1].
        // swap(d=pB_[2c], s=pB_[2c+1]) -> new_d rows {d0,s0,d2,s2}, new_s rows
        // {d1,s1,d3,s3}; assembled frag at quad q covers j-group {0,2,1,3}[q].
        u32 pB_[4][2];
        #pragma unroll
        for (int nt = 0; nt < 4; ++nt) {
            pB_[nt][0] = cvtpk_bf16(__expf(sB[nt][0]), __expf(sB[nt][1]));
            pB_[nt][1] = cvtpk_bf16(__expf(sB[nt][2]), __expf(sB[nt][3]));
        }
        #pragma unroll
        for (int c = 0; c < 2; ++c)
            #pragma unroll
            for (int p = 0; p < 2; ++p) {
                u32x2 sw = __builtin_amdgcn_permlane16_swap(
                    pB_[2 * c][p], pB_[2 * c + 1][p], false, false);
                pB_[2 * c][p] = sw[0];
                pB_[2 * c + 1][p] = sw[1];
            }
        union { u32 u[4]; bf16x8 v; } ub0, ub1;
        ub0.u[0] = pB_[0][0]; ub0.u[1] = pB_[0][1];
        ub0.u[2] = pB_[1][0]; ub0.u[3] = pB_[1][1];
        ub1.u[0] = pB_[2][0]; ub1.u[1] = pB_[2][1];
        ub1.u[2] = pB_[3][0]; ub1.u[3] = pB_[3][1];
        bf16x8 aB0 = ub0.v, aB1 = ub1.v;

        bf16x8 aA0, aA1;
        if (doA) {
            u32 pA_[4][2];
            #pragma unroll
            for (int nt = 0; nt < 4; ++nt) {
                pA_[nt][0] = cvtpk_bf16(__expf(sA[nt][0]), __expf(sA[nt][1]));
                pA_[nt][1] = cvtpk_bf16(__expf(sA[nt][2]), __expf(sA[nt][3]));
            }
            #pragma unroll
            for (int c = 0; c < 2; ++c)
                #pragma unroll
                for (int p = 0; p < 2; ++p) {
                    u32x2 sw = __builtin_amdgcn_permlane16_swap(
                        pA_[2 * c][p], pA_[2 * c + 1][p], false, false);
                    pA_[2 * c][p] = sw[0];
                    pA_[2 * c + 1][p] = sw[1];
                }
            union { u32 u[4]; bf16x8 v; } ua0, ua1;
            ua0.u[0] = pA_[0][0]; ua0.u[1] = pA_[0][1];
            ua0.u[2] = pA_[1][0]; ua0.u[3] = pA_[1][1];
            ua1.u[0] = pA_[2][0]; ua1.u[1] = pA_[2][1];
            ua1.u[2] = pA_[3][0]; ua1.u[3] = pA_[3][1];
            aA0 = ua0.v; aA1 = ua1.v;
        }

        // ---- l via ones-MFMA (k-permutation invariant) ----
        laB = MFMA_BF(aB0, ones, laB);
        laB = MFMA_BF(aB1, ones, laB);
        if (doA) {
            laA = MFMA_BF(aA0, ones, laA);
            laA = MFMA_BF(aA1, ones, laA);
        }

        // ---- PV, sharing bv fragments; V read at logical chunk pi(quad) ----
        #pragma unroll
        for (int dt = 0; dt < 4; ++dt) {
            const int vrow = dt * 16 + l15;
            bf16x8 v0 = *(const bf16x8*)&Vs[buf][vrow * 64 + ((pq + vrow) & 7) * 8];
            bf16x8 v1 = *(const bf16x8*)&Vs[buf][vrow * 64 + ((pq + 4 + vrow) & 7) * 8];
            oB[dt] = MFMA_BF(aB0, v0, oB[dt]);
            oB[dt] = MFMA_BF(aB1, v1, oB[dt]);
            if (doA) {
                oA[dt] = MFMA_BF(aA0, v0, oA[dt]);
                oA[dt] = MFMA_BF(aA1, v1, oA[dt]);
            }
        }
    }

    // ---- epilogue: store UN-NORMALIZED partials (o, l) for this half ----
    #pragma unroll
    for (int dt = 0; dt < 4; ++dt) {
        #pragma unroll
        for (int r = 0; r < 4; ++r) {
            const int igA = i0A + w * 16 + quad * 4 + r;
            const int igB = i0B + w * 16 + quad * 4 + r;
            po[((size_t)half * BT + rowbase + igA) * CC + hd + dt * 16 + l15] = oA[dt][r];
            po[((size_t)half * BT + rowbase + igB) * CC + hd + dt * 16 + l15] = oB[dt][r];
        }
    }
    if (l15 == 0) {
        #pragma unroll
        for (int r = 0; r < 4; ++r) {
            const int igA = i0A + w * 16 + quad * 4 + r;
            const int igB = i0B + w * 16 + quad * 4 + r;
            pl[((size_t)half * BT + rowbase + igA) * NHH + h] = laA[r];
            pl[((size_t)half * BT + rowbase + igB) * NHH + h] = laB[r];
        }
    }
}

// ---------------------------------------------------------------------------
// combine: out = (o0 + o1) / (l0 + l1). 4096 blocks x 256 thr, float4.
// ---------------------------------------------------------------------------
__global__ __launch_bounds__(256) void combine_kernel(
    const float* __restrict__ po, const float* __restrict__ pl,
    float* __restrict__ out)
{
    const int gid = blockIdx.x * 256 + threadIdx.x;   // 0 .. 4096*256-1
    const int row = gid >> 8, c4 = gid & 255;
    const int h = c4 >> 4;
    const float l0 = pl[(size_t)row * NHH + h];
    const float l1 = pl[(size_t)(BT + row) * NHH + h];
    const float inv = 1.f / (l0 + l1);
    const float4 o0 = *(const float4*)&po[(size_t)row * CC + c4 * 4];
    const float4 o1 = *(const float4*)&po[(size_t)(BT + row) * CC + c4 * 4];
    float4 o;
    o.x = (o0.x + o1.x) * inv;
    o.y = (o0.y + o1.y) * inv;
    o.z = (o0.z + o1.z) * inv;
    o.w = (o0.w + o1.w) * inv;
    *(float4*)&out[(size_t)row * CC + c4 * 4] = o;
}

extern "C" void kernel_launch(void* const* d_in, const int* in_sizes, int n_in,
                              void* d_out, int out_size, void* d_ws, size_t ws_size,
                              hipStream_t stream) {
    (void)in_sizes; (void)n_in; (void)out_size; (void)ws_size;
    const float* x  = (const float*)d_in[0];
    const float* Wk = (const float*)d_in[1];
    const float* bk = (const float*)d_in[2];
    const float* Wv = (const float*)d_in[3];
    const float* bv = (const float*)d_in[4];
    float* out = (float*)d_out;

    const size_t M4 = (size_t)BT * CC;   // 4M elements
    const size_t M1 = (size_t)CC * CC;   // 1M elements
    u16* Xf  = (u16*)d_ws;               // fp16, 8 MB
    u16* Kf  = Xf + M4;                  // fp16, 8 MB
    u16* Vt  = Kf + M4;                  // bf16, 8 MB
    u16* WkT = Vt + M4;                  // fp16, 2 MB
    u16* WvT = WkT + M1;                 // fp16, 2 MB  (28 MB)
    float* po = (float*)(WvT + M1);      // fp32 [2][BT][CC], 32 MB
    float* pl = po + (size_t)2 * BT * CC;// fp32 [2][BT][NHH], 0.5 MB (60.5 MB)

    convert_x<<<dim3(M4 / (256 * 8)), 256, 0, stream>>>(x, Xf);
    convert_w<<<dim3(16, 16, 2), 256, 0, stream>>>(Wk, Wv, WkT, WvT);
    proj_kernel<<<dim3(512), 256, 0, stream>>>(Xf, WkT, WvT, bk, bv, Kf, Vt);
    attn_kernel<<<dim3(1024), 256, 0, stream>>>(Xf, Kf, Vt, po, pl);
    combine_kernel<<<dim3(4096), 256, 0, stream>>>(po, pl, out);
}

// Round 5
// 153.905 us; speedup vs baseline: 1.0375x; 1.0375x over previous
//
#include <hip/hip_runtime.h>
#include <cstdint>
#include <cstddef>

#define BB  2
#define TT  2048
#define CC  1024
#define NHH 16
#define HSS 64
#define BT  (BB*TT)   // 4096

#define LOG2E 1.44269504088896f
#define S0INIT (-28.8539008f)   // -20 * log2(e)

typedef unsigned short u16;
typedef unsigned int u32;
typedef __attribute__((ext_vector_type(2))) unsigned int u32x2;
typedef _Float16 f16;
typedef __attribute__((ext_vector_type(8))) _Float16 f16x8;
typedef __attribute__((ext_vector_type(8))) __bf16 bf16x8;
typedef __attribute__((ext_vector_type(4))) float f32x4;

__device__ __forceinline__ u16 f2bf(float f) {
    union { float f; u32 u; } x; x.f = f;
    return (u16)((x.u + 0x7fffu + ((x.u >> 16) & 1u)) >> 16);
}
__device__ __forceinline__ u16 f2h(float f) {
    union { f16 h; u16 u; } x; x.h = (f16)f;
    return x.u;
}
// packed f32 pair -> bf16x2 in one u32 (RNE), single VALU op
__device__ __forceinline__ u32 cvtpk_bf16(float lo, float hi) {
    u32 r;
    asm("v_cvt_pk_bf16_f32 %0, %1, %2" : "=v"(r) : "v"(lo), "v"(hi));
    return r;
}

#define MFMA_BF(a,b,c) __builtin_amdgcn_mfma_f32_16x16x32_bf16((a),(b),(c),0,0,0)
#define MFMA_F16(a,b,c) __builtin_amdgcn_mfma_f32_16x16x32_f16((a),(b),(c),0,0,0)

// async global->LDS, 16B/lane; LDS dest = wave-uniform base + lane*16
__device__ __forceinline__ void gld16(const u16* g, u16* l) {
    __builtin_amdgcn_global_load_lds(
        (const __attribute__((address_space(1))) unsigned int*)g,
        (__attribute__((address_space(3))) unsigned int*)l, 16, 0, 0);
}

// ---------------------------------------------------------------------------
// convert_x: x fp32 -> Xf fp16.
// ---------------------------------------------------------------------------
__global__ __launch_bounds__(256) void convert_x(
    const float* __restrict__ X, u16* __restrict__ Xf)
{
    const int idx = (blockIdx.x * 256 + threadIdx.x) * 8;
    const float4 a = *(const float4*)&X[idx];
    const float4 b = *(const float4*)&X[idx + 4];
    float v[8] = {a.x, a.y, a.z, a.w, b.x, b.y, b.z, b.w};
    union { uint4 u; u16 s[8]; } H;
    #pragma unroll
    for (int u = 0; u < 8; ++u) H.s[u] = f2h(v[u]);
    *(uint4*)&Xf[idx] = H.u;
}

// ---------------------------------------------------------------------------
// convert_w: W [k][n] fp32 -> WT [n][k] fp16 (z=0: Wk, z=1: Wv).
// ---------------------------------------------------------------------------
__global__ __launch_bounds__(256) void convert_w(
    const float* __restrict__ Wk, const float* __restrict__ Wv,
    u16* __restrict__ WkT, u16* __restrict__ WvT)
{
    const bool isK = (blockIdx.z == 0);
    const float* W = isK ? Wk : Wv;
    u16* WT = isK ? WkT : WvT;
    __shared__ __align__(16) u16 LH[64][72];
    const int tid = threadIdx.x;
    const int k0 = blockIdx.y * 64, n0 = blockIdx.x * 64;
    {
        const int row = tid >> 2, coff = (tid & 3) * 16;
        const float* g = &W[(size_t)(k0 + row) * CC + n0 + coff];
        #pragma unroll
        for (int u = 0; u < 16; ++u) LH[row][coff + u] = f2h(g[u]);
    }
    __syncthreads();
    {
        const int n = tid >> 2, kc = (tid & 3) * 16;
        union { uint4 u[2]; u16 s[16]; } Hq;
        #pragma unroll
        for (int u = 0; u < 16; ++u) Hq.s[u] = LH[kc + u][n];
        uint4* ph = (uint4*)&WT[(size_t)(n0 + n) * CC + k0 + kc];
        ph[0] = Hq.u[0]; ph[1] = Hq.u[1];
    }
}

// ---------------------------------------------------------------------------
// proj_kernel: 128x128 fp16 GEMM, BK=64, double-buffered gld16 staging.
// k-loop UNROLLED x2 so the LDS buffer index is a compile-time literal and
// every ds_read_b128 is base-VGPR + immediate (no per-iter address VALU).
// z=0: Kproj -> Kf fp16 [t][c], PRE-SCALED by log2(e) (consumed only by the
// attn logits; lets attn use exp2 with no per-element multiply).
// z=1: V -> Vt bf16 head-transposed [b][h][d][T].
// ---------------------------------------------------------------------------
__global__ __launch_bounds__(256) void proj_kernel(
    const u16* __restrict__ Xf, const u16* __restrict__ WkT,
    const u16* __restrict__ WvT,
    const float* __restrict__ bk, const float* __restrict__ bv,
    u16* __restrict__ Kf, u16* __restrict__ Vt)
{
    __shared__ __align__(16) u16 SM[4][8192];  // A dbuf / B dbuf; epilogue reuse

    const int id = blockIdx.x;
    const int xcd = id & 7, idx = id >> 3;
    const int z = idx >> 5, rem = idx & 31;
    const int n0 = (rem & 7) * 128;
    const int m0 = (xcd * 4 + (rem >> 3)) * 128;
    const bool isK = (z == 0);
    const u16* WT = isK ? WkT : WvT;

    const int tid = threadIdx.x;
    const int w = tid >> 6, lane = tid & 63;
    const int quad = lane >> 4, l15 = lane & 15;
    const int wm = (w >> 1) * 64, wn = (w & 1) * 64;

    // staging: waves 0,1 -> A (Xf rows m0..), waves 2,3 -> B (WT rows n0..)
    const u16* src = (w < 2) ? Xf : WT;
    const int rb = (w < 2) ? m0 : n0;
    int srow[8], scg[8];
    #pragma unroll
    for (int t = 0; t < 8; ++t) {
        int ci = (w & 1) * 512 + t * 64 + lane;
        srow[t] = ci >> 3;
        scg[t] = ((ci & 7) - srow[t]) & 7;
    }
    const int sbase = (w & 1) * 4096;

    // per-thread LDS base pointers (byte); reads add BUF*16384 + i*2048 imm
    const char* smA0 = (const char*)&SM[0][0] + (wm + l15) * 128 +
                       ((quad + wm + l15) & 7) * 16;
    const char* smA1 = (const char*)&SM[0][0] + (wm + l15) * 128 +
                       ((4 + quad + wm + l15) & 7) * 16;
    const char* smB0 = (const char*)&SM[0][0] + 32768 + (wn + l15) * 128 +
                       ((quad + wn + l15) & 7) * 16;
    const char* smB1 = (const char*)&SM[0][0] + 32768 + (wn + l15) * 128 +
                       ((4 + quad + wn + l15) & 7) * 16;

    f32x4 acc[4][4] = {};

    // prologue stage k=0 into buf 0
    {
        u16* dst = ((w < 2) ? SM[0] : SM[2]) + sbase;
        #pragma unroll
        for (int t = 0; t < 8; ++t)
            gld16(src + (size_t)(rb + srow[t]) * CC + scg[t] * 8, dst + t * 512);
    }

#define PROJ_STEP(KI, BUF)                                                    \
    {                                                                         \
        __syncthreads();                                                      \
        if ((KI) < 15) {                                                      \
            u16* dst = ((w < 2) ? SM[(BUF) ^ 1] : SM[2 + ((BUF) ^ 1)]) + sbase;\
            const int k0n = ((KI) + 1) * 64;                                  \
            _Pragma("unroll")                                                 \
            for (int t = 0; t < 8; ++t)                                       \
                gld16(src + (size_t)(rb + srow[t]) * CC + k0n + scg[t] * 8,   \
                      dst + t * 512);                                         \
        }                                                                     \
        _Pragma("unroll")                                                     \
        for (int kk = 0; kk < 2; ++kk) {                                      \
            const char* pa = kk ? smA1 : smA0;                                \
            const char* pb = kk ? smB1 : smB0;                                \
            f16x8 ah[4];                                                      \
            _Pragma("unroll")                                                 \
            for (int i = 0; i < 4; ++i)                                       \
                ah[i] = *(const f16x8*)(pa + (BUF) * 16384 + i * 2048);       \
            _Pragma("unroll")                                                 \
            for (int j = 0; j < 4; ++j) {                                     \
                f16x8 bh_ = *(const f16x8*)(pb + (BUF) * 16384 + j * 2048);   \
                _Pragma("unroll")                                             \
                for (int i = 0; i < 4; ++i)                                   \
                    acc[i][j] = MFMA_F16(ah[i], bh_, acc[i][j]);              \
            }                                                                 \
        }                                                                     \
    }

    for (int ki = 0; ki < 16; ki += 2) {
        PROJ_STEP(ki, 0);
        PROJ_STEP(ki + 1, 1);
    }
#undef PROJ_STEP

    __syncthreads();               // all compute done; reuse SM for epilogue
    u16* XL = &SM[0][0];           // stride 136 (17408 u16 = 34 KB)

    if (isK) {
        #pragma unroll
        for (int j = 0; j < 4; ++j) {
            const float bias = bk[n0 + wn + j * 16 + l15];
            #pragma unroll
            for (int i = 0; i < 4; ++i)
                #pragma unroll
                for (int r = 0; r < 4; ++r)
                    XL[(wm + i * 16 + quad * 4 + r) * 136 + wn + j * 16 + l15] =
                        f2h((acc[i][j][r] + bias) * LOG2E);
        }
        __syncthreads();
        const int r = tid >> 1, half = tid & 1;
        #pragma unroll
        for (int t = 0; t < 8; ++t)
            *(uint4*)&Kf[(size_t)(m0 + r) * CC + n0 + half * 64 + t * 8] =
                *(const uint4*)&XL[r * 136 + half * 64 + t * 8];
    } else {
        // write transposed [n-local][t-local]: 4 consecutive t -> uint2
        #pragma unroll
        for (int j = 0; j < 4; ++j) {
            const float bias = bv[n0 + wn + j * 16 + l15];
            #pragma unroll
            for (int i = 0; i < 4; ++i) {
                uint2 pk;
                pk.x = (u32)f2bf(acc[i][j][0] + bias) |
                       ((u32)f2bf(acc[i][j][1] + bias) << 16);
                pk.y = (u32)f2bf(acc[i][j][2] + bias) |
                       ((u32)f2bf(acc[i][j][3] + bias) << 16);
                *(uint2*)&XL[(wn + j * 16 + l15) * 136 + wm + i * 16 + quad * 4] = pk;
            }
        }
        __syncthreads();
        const int nl = tid >> 1, half = tid & 1;
        const int d = (n0 + nl) & (HSS - 1), hh = (n0 + nl) >> 6;
        const int bb = m0 >> 11, tb = (m0 & (TT - 1)) + half * 64;
        const size_t gb = ((size_t)(bb * NHH + hh) * HSS + d) * TT + tb;
        #pragma unroll
        for (int t = 0; t < 8; ++t)
            *(uint4*)&Vt[gb + t * 8] = *(const uint4*)&XL[nl * 136 + half * 64 + t * 8];
    }
}

// ---------------------------------------------------------------------------
// attn: paired i-tiles (k, 31-k) -> 512 uniform blocks, XCD swizzle.
// NON-SPLIT (R4's parity split bought 0 in attn and cost ~10us in combine).
// VALU diet vs R1/R4:
//  - j-loop unrolled x2: LDS buffer index is a compile-time literal; all
//    ds_read_b128 are per-thread base VGPR + immediate (no addr math/iter).
//  - Kf pre-scaled by log2(e) at proj: exp2f (bare v_exp), no v_mul; softmax
//    bias folded into MFMA C-init (-20*log2e).
//  - P entirely in registers (R4-verified): cvt_pk_bf16 + BUILTIN
//    permlane16_swap; k-groups land permuted pi={0,2,1,3}, compensated by
//    reading V B-fragments at chunk pi(quad).
// ---------------------------------------------------------------------------
__global__ __launch_bounds__(256) void attn_kernel(
    const u16* __restrict__ Xf, const u16* __restrict__ Kf,
    const u16* __restrict__ Vt, float* __restrict__ out)
{
    __shared__ __align__(16) u16 Xs[2][4096];  // x rows [j][d], chunk-swizzled
    __shared__ __align__(16) u16 Vs[2][4096];  // V^T [d][j], chunk-swizzled

    const int L = blockIdx.x;
    const int xcd = L & 7, k = (L >> 3) & 15, grp = L >> 7;
    const int hb = xcd + 8 * grp;
    const int h = hb & (NHH - 1), b = hb >> 4;
    const int iA = k, iB = 31 - k;
    const int i0A = iA * 64, i0B = iB * 64;

    const int tid = threadIdx.x;
    const int w = tid >> 6, lane = tid & 63;
    const int quad = lane >> 4, l15 = lane & 15;
    const int pq = ((quad & 1) << 1) | (quad >> 1);      // pi(quad)={0,2,1,3}
    const size_t rowbase = (size_t)b * TT;
    const int hd = h * HSS;
    const size_t vgbase = (size_t)(b * NHH + h) * HSS * TT;

    bf16x8 ones;
    { union { u32 u[4]; bf16x8 v; } o;
      #pragma unroll
      for (int i = 0; i < 4; ++i) o.u[i] = 0x3F803F80u;
      ones = o.v; }

    // hoist Q (projected-K, log2e-scaled) B-fragments for both tiles
    f16x8 qA[2], qB[2];
    #pragma unroll
    for (int c = 0; c < 2; ++c) {
        qA[c] = *(const f16x8*)&Kf[(rowbase + i0A + w * 16 + l15) * CC + hd + c * 32 + quad * 8];
        qB[c] = *(const f16x8*)&Kf[(rowbase + i0B + w * 16 + l15) * CC + hd + c * 32 + quad * 8];
    }

    // per-thread LDS base pointers (byte); reads add BUF*8192 + nt*2048 imm
    const char* xs0 = (const char*)&Xs[0][0] + l15 * 128 + ((quad + l15) & 7) * 16;
    const char* xs1 = (const char*)&Xs[0][0] + l15 * 128 + ((quad + 4 + l15) & 7) * 16;
    const char* vs0 = (const char*)&Vs[0][0] + l15 * 128 + ((pq + l15) & 7) * 16;
    const char* vs1 = (const char*)&Vs[0][0] + l15 * 128 + ((pq + 4 + l15) & 7) * 16;

    // gld16 staging descriptors: 2 chunks per lane per array
    int crow[2], ccg[2], cbase[2];
    #pragma unroll
    for (int t = 0; t < 2; ++t) {
        const int ci = t * 256 + tid;
        crow[t] = ci >> 3;
        ccg[t] = ((ci & 7) - crow[t]) & 7;
        cbase[t] = (t * 256 + w * 64) * 8;
    }
    const u16* gx[2]; const u16* gv[2];
    #pragma unroll
    for (int t = 0; t < 2; ++t) {
        gx[t] = Xf + (rowbase + crow[t]) * CC + hd + ccg[t] * 8;
        gv[t] = Vt + vgbase + (size_t)crow[t] * TT + ccg[t] * 8;
    }

    // prologue: stage tile jt=0 into buf 0
    #pragma unroll
    for (int t = 0; t < 2; ++t) {
        gld16(gx[t], Xs[0] + cbase[t]);
        gld16(gv[t], Vs[0] + cbase[t]);
    }

    f32x4 oA[4] = {}, oB[4] = {};
    f32x4 laA = {}, laB = {};

#define ATTN_BODY(JT, BUF)                                                    \
    {                                                                         \
        __syncthreads();                                                      \
        if ((JT) + 1 <= iB) {                                                 \
            const int j0n = ((JT) + 1) * 64;                                  \
            _Pragma("unroll")                                                 \
            for (int t = 0; t < 2; ++t) {                                     \
                gld16(gx[t] + (size_t)j0n * CC, Xs[(BUF) ^ 1] + cbase[t]);    \
                gld16(gv[t] + j0n, Vs[(BUF) ^ 1] + cbase[t]);                 \
            }                                                                 \
        }                                                                     \
        const bool doA_ = (JT) <= iA;                                         \
        f32x4 sB[4], sA[4];                                                   \
        _Pragma("unroll")                                                     \
        for (int nt = 0; nt < 4; ++nt) {                                      \
            f16x8 x0 = *(const f16x8*)(xs0 + (BUF) * 8192 + nt * 2048);       \
            f16x8 x1 = *(const f16x8*)(xs1 + (BUF) * 8192 + nt * 2048);       \
            f32x4 z = {S0INIT, S0INIT, S0INIT, S0INIT};                       \
            z = MFMA_F16(x0, qB[0], z);                                       \
            z = MFMA_F16(x1, qB[1], z);                                       \
            sB[nt] = z;                                                       \
            if (doA_) {                                                       \
                f32x4 y = {S0INIT, S0INIT, S0INIT, S0INIT};                   \
                y = MFMA_F16(x0, qA[0], y);                                   \
                y = MFMA_F16(x1, qA[1], y);                                   \
                sA[nt] = y;                                                   \
            }                                                                 \
        }                                                                     \
        if ((JT) == iB) {                                                     \
            _Pragma("unroll")                                                 \
            for (int nt = 0; nt < 4; ++nt)                                    \
                _Pragma("unroll")                                             \
                for (int r = 0; r < 4; ++r)                                   \
                    if (nt * 16 + quad * 4 + r > w * 16 + l15)                \
                        sB[nt][r] = -1e30f;                                   \
        }                                                                     \
        if (doA_ && (JT) == iA) {                                             \
            _Pragma("unroll")                                                 \
            for (int nt = 0; nt < 4; ++nt)                                    \
                _Pragma("unroll")                                             \
                for (int r = 0; r < 4; ++r)                                   \
                    if (nt * 16 + quad * 4 + r > w * 16 + l15)                \
                        sA[nt][r] = -1e30f;                                   \
        }                                                                     \
        u32 pB_[4][2];                                                        \
        _Pragma("unroll")                                                     \
        for (int nt = 0; nt < 4; ++nt) {                                      \
            pB_[nt][0] = cvtpk_bf16(exp2f(sB[nt][0]), exp2f(sB[nt][1]));      \
            pB_[nt][1] = cvtpk_bf16(exp2f(sB[nt][2]), exp2f(sB[nt][3]));      \
        }                                                                     \
        _Pragma("unroll")                                                     \
        for (int c = 0; c < 2; ++c)                                           \
            _Pragma("unroll")                                                 \
            for (int p = 0; p < 2; ++p) {                                     \
                u32x2 sw = __builtin_amdgcn_permlane16_swap(                  \
                    pB_[2 * c][p], pB_[2 * c + 1][p], false, false);          \
                pB_[2 * c][p] = sw[0];                                        \
                pB_[2 * c + 1][p] = sw[1];                                    \
            }                                                                 \
        union { u32 u[4]; bf16x8 v; } ub0, ub1;                               \
        ub0.u[0] = pB_[0][0]; ub0.u[1] = pB_[0][1];                           \
        ub0.u[2] = pB_[1][0]; ub0.u[3] = pB_[1][1];                           \
        ub1.u[0] = pB_[2][0]; ub1.u[1] = pB_[2][1];                           \
        ub1.u[2] = pB_[3][0]; ub1.u[3] = pB_[3][1];                           \
        bf16x8 aB0 = ub0.v, aB1 = ub1.v;                                      \
        bf16x8 aA0, aA1;                                                      \
        if (doA_) {                                                           \
            u32 pA_[4][2];                                                    \
            _Pragma("unroll")                                                 \
            for (int nt = 0; nt < 4; ++nt) {                                  \
                pA_[nt][0] = cvtpk_bf16(exp2f(sA[nt][0]), exp2f(sA[nt][1]));  \
                pA_[nt][1] = cvtpk_bf16(exp2f(sA[nt][2]), exp2f(sA[nt][3]));  \
            }                                                                 \
            _Pragma("unroll")                                                 \
            for (int c = 0; c < 2; ++c)                                       \
                _Pragma("unroll")                                             \
                for (int p = 0; p < 2; ++p) {                                 \
                    u32x2 sw = __builtin_amdgcn_permlane16_swap(              \
                        pA_[2 * c][p], pA_[2 * c + 1][p], false, false);      \
                    pA_[2 * c][p] = sw[0];                                    \
                    pA_[2 * c + 1][p] = sw[1];                                \
                }                                                             \
            union { u32 u[4]; bf16x8 v; } ua0, ua1;                           \
            ua0.u[0] = pA_[0][0]; ua0.u[1] = pA_[0][1];                       \
            ua0.u[2] = pA_[1][0]; ua0.u[3] = pA_[1][1];                       \
            ua1.u[0] = pA_[2][0]; ua1.u[1] = pA_[2][1];                       \
            ua1.u[2] = pA_[3][0]; ua1.u[3] = pA_[3][1];                       \
            aA0 = ua0.v; aA1 = ua1.v;                                         \
        }                                                                     \
        laB = MFMA_BF(aB0, ones, laB);                                        \
        laB = MFMA_BF(aB1, ones, laB);                                        \
        if (doA_) {                                                           \
            laA = MFMA_BF(aA0, ones, laA);                                    \
            laA = MFMA_BF(aA1, ones, laA);                                    \
        }                                                                     \
        _Pragma("unroll")                                                     \
        for (int dt = 0; dt < 4; ++dt) {                                      \
            bf16x8 v0 = *(const bf16x8*)(vs0 + (BUF) * 8192 + dt * 2048);     \
            bf16x8 v1 = *(const bf16x8*)(vs1 + (BUF) * 8192 + dt * 2048);     \
            oB[dt] = MFMA_BF(aB0, v0, oB[dt]);                                \
            oB[dt] = MFMA_BF(aB1, v1, oB[dt]);                                \
            if (doA_) {                                                       \
                oA[dt] = MFMA_BF(aA0, v0, oA[dt]);                            \
                oA[dt] = MFMA_BF(aA1, v1, oA[dt]);                            \
            }                                                                 \
        }                                                                     \
    }

    for (int jt = 0; jt <= iB; jt += 2) {
        ATTN_BODY(jt, 0);
        if (jt + 1 <= iB) ATTN_BODY(jt + 1, 1);
    }
#undef ATTN_BODY

    // ---- epilogue: normalize, fp32 store, both tiles ----
    float liA[4], liB[4];
    #pragma unroll
    for (int r = 0; r < 4; ++r) { liA[r] = 1.f / laA[r]; liB[r] = 1.f / laB[r]; }
    #pragma unroll
    for (int dt = 0; dt < 4; ++dt) {
        #pragma unroll
        for (int r = 0; r < 4; ++r) {
            const int igA = i0A + w * 16 + quad * 4 + r;
            const int igB = i0B + w * 16 + quad * 4 + r;
            out[(rowbase + igA) * CC + hd + dt * 16 + l15] = oA[dt][r] * liA[r];
            out[(rowbase + igB) * CC + hd + dt * 16 + l15] = oB[dt][r] * liB[r];
        }
    }
}

extern "C" void kernel_launch(void* const* d_in, const int* in_sizes, int n_in,
                              void* d_out, int out_size, void* d_ws, size_t ws_size,
                              hipStream_t stream) {
    (void)in_sizes; (void)n_in; (void)out_size; (void)ws_size;
    const float* x  = (const float*)d_in[0];
    const float* Wk = (const float*)d_in[1];
    const float* bk = (const float*)d_in[2];
    const float* Wv = (const float*)d_in[3];
    const float* bv = (const float*)d_in[4];
    float* out = (float*)d_out;

    const size_t M4 = (size_t)BT * CC;   // 4M elements
    const size_t M1 = (size_t)CC * CC;   // 1M elements
    u16* Xf  = (u16*)d_ws;               // fp16, 8 MB
    u16* Kf  = Xf + M4;                  // fp16 (log2e-scaled), 8 MB
    u16* Vt  = Kf + M4;                  // bf16, 8 MB
    u16* WkT = Vt + M4;                  // fp16, 2 MB
    u16* WvT = WkT + M1;                 // fp16, 2 MB  (28 MB total)

    convert_x<<<dim3(M4 / (256 * 8)), 256, 0, stream>>>(x, Xf);
    convert_w<<<dim3(16, 16, 2), 256, 0, stream>>>(Wk, Wv, WkT, WvT);
    proj_kernel<<<dim3(512), 256, 0, stream>>>(Xf, WkT, WvT, bk, bv, Kf, Vt);
    attn_kernel<<<dim3(512), 256, 0, stream>>>(Xf, Kf, Vt, out);
}